// Round 15
// baseline (199.602 us; speedup 1.0000x reference)
//
#include <hip/hip_runtime.h>
#include <math.h>

#define NZd 128
#define NXd 256
#define NYd 256
#define NVOX (NZd * NXd * NYd)   // 8,388,608 voxels
#define PI_F 3.14159265358979323846f
#define SCALE_ORTHO 3.4526698300124393e-4f  // 1/sqrt(128*256*256)
#define CAP 512                  // LDS survivor-list capacity

// ---------------------------------------------------------------------------
// Zero helper (guard path only).
// ---------------------------------------------------------------------------
__global__ void zero_kernel(float4* __restrict__ p, int n4) {
    int i = blockIdx.x * blockDim.x + threadIdx.x;
    if (i < n4) p[i] = make_float4(0.f, 0.f, 0.f, 0.f);
}

// ---------------------------------------------------------------------------
// Legacy atomic voxelize (fallback / interleaved path only).
// ---------------------------------------------------------------------------
__global__ void voxelize_kernel(const float* __restrict__ centers,
                                const float* __restrict__ log_scales,
                                const float* __restrict__ rho_r,
                                const float* __restrict__ rho_i,
                                float* __restrict__ vol, int M) {
    long long t = (long long)blockIdx.x * blockDim.x + threadIdx.x;
    if (t >= (long long)M * 343) return;
    int g = (int)(t / 343);
    int k = (int)(t % 343);
    int oz = k / 49 - 3, ox = (k / 7) % 7 - 3, oy = k % 7 - 3;
    float cz = centers[g * 3 + 0], cx = centers[g * 3 + 1], cy = centers[g * 3 + 2];
    int iz = (int)rintf((cz + 1.0f) * 0.5f * 127.0f);
    int ix = (int)rintf((cx + 1.0f) * 0.5f * 255.0f);
    int iy = (int)rintf((cy + 1.0f) * 0.5f * 255.0f);
    int nz = iz + oz, nx = ix + ox, ny = iy + oy;
    if (nz < 0 || nz >= NZd || nx < 0 || nx >= NXd || ny < 0 || ny >= NYd) return;
    float sz = expf(log_scales[g * 3 + 0]) + 1e-8f;
    float sx = expf(log_scales[g * 3 + 1]) + 1e-8f;
    float sy = expf(log_scales[g * 3 + 2]) + 1e-8f;
    float dz = ((float)nz / 127.0f * 2.0f - 1.0f - cz) / sz;
    float dx = ((float)nx / 255.0f * 2.0f - 1.0f - cx) / sx;
    float dy = ((float)ny / 255.0f * 2.0f - 1.0f - cy) / sy;
    float d2 = dz * dz + dx * dx + dy * dy;
    if (d2 > 9.0f) return;
    float w = expf(-0.5f * d2);
    int idx = (nz * NXd + nx) * NYd + ny;
    atomicAdd(&vol[2 * idx + 0], rho_r[g] * w);
    atomicAdd(&vol[2 * idx + 1], rho_i[g] * w);
}

__global__ void copy_real_kernel(const float2* __restrict__ cvol,
                                 float* __restrict__ out) {
    int i = blockIdx.x * blockDim.x + threadIdx.x;
    out[i] = cvol[i].x;
}

// ---------------------------------------------------------------------------
// Binning: count -> scan -> scatter precomputed gaussian records.
// Bin = 16^3 cell of the nearest-voxel center: 8 x 16 x 16 = 2048 bins.
// ---------------------------------------------------------------------------
__device__ __forceinline__ void center_voxel(const float* __restrict__ centers,
                                             int g, int& iz, int& ix, int& iy) {
    float cz = centers[g * 3 + 0], cx = centers[g * 3 + 1], cy = centers[g * 3 + 2];
    iz = min(max((int)rintf((cz + 1.0f) * 0.5f * 127.0f), 0), 127);
    ix = min(max((int)rintf((cx + 1.0f) * 0.5f * 255.0f), 0), 255);
    iy = min(max((int)rintf((cy + 1.0f) * 0.5f * 255.0f), 0), 255);
}

__global__ void bin_count_kernel(const float* __restrict__ centers,
                                 int* __restrict__ cnt, int M) {
    int g = blockIdx.x * blockDim.x + threadIdx.x;
    if (g >= M) return;
    int iz, ix, iy;
    center_voxel(centers, g, iz, ix, iy);
    atomicAdd(&cnt[((iz >> 4) << 8) | ((ix >> 4) << 4) | (iy >> 4)], 1);
}

// one wave scans 2048 counts -> exclusive offsets (+ cursor copy)
__global__ void bin_scan_kernel(const int* __restrict__ cnt,
                                int* __restrict__ off,
                                int* __restrict__ cursor) {
    int lane = threadIdx.x;      // 64 threads
    int base = lane << 5;        // 32 bins per lane
    int s = 0;
    #pragma unroll
    for (int i = 0; i < 32; i++) s += cnt[base + i];
    int incl = s;
    #pragma unroll
    for (int d = 1; d < 64; d <<= 1) {
        int v = __shfl_up(incl, d, 64);
        if (lane >= d) incl += v;
    }
    int run = incl - s;          // exclusive prefix of this lane's chunk
    for (int i = 0; i < 32; i++) {
        int c = cnt[base + i];
        off[base + i] = run;
        cursor[base + i] = run;
        run += c;
    }
}

__global__ void bin_scatter_kernel(const float* __restrict__ centers,
                                   const float* __restrict__ log_scales,
                                   const float* __restrict__ rho_r,
                                   const float* __restrict__ rho_i,
                                   int* __restrict__ cursor,
                                   int* __restrict__ ciA,
                                   float* __restrict__ czA, float* __restrict__ cxA,
                                   float* __restrict__ cyA,
                                   float* __restrict__ iszA, float* __restrict__ isxA,
                                   float* __restrict__ isyA,
                                   float* __restrict__ rrA, float* __restrict__ riA,
                                   int M) {
    int g = blockIdx.x * blockDim.x + threadIdx.x;
    if (g >= M) return;
    int iz, ix, iy;
    center_voxel(centers, g, iz, ix, iy);
    int b = ((iz >> 4) << 8) | ((ix >> 4) << 4) | (iy >> 4);
    int pos = atomicAdd(&cursor[b], 1);
    ciA[pos] = (iz << 16) | (ix << 8) | iy;
    czA[pos] = centers[g * 3 + 0];
    cxA[pos] = centers[g * 3 + 1];
    cyA[pos] = centers[g * 3 + 2];
    iszA[pos] = 1.0f / (expf(log_scales[g * 3 + 0]) + 1e-8f);
    isxA[pos] = 1.0f / (expf(log_scales[g * 3 + 1]) + 1e-8f);
    isyA[pos] = 1.0f / (expf(log_scales[g * 3 + 2]) + 1e-8f);
    rrA[pos] = rho_r[g];
    riA[pos] = rho_i[g];
}

// ---------------------------------------------------------------------------
// Tile accumulation, 16x16x8 tiles (4096 blocks): flattened cull (round 14),
// packed-record process: sci (b32) + srA=(cx,cy,isx,isy) + srB=(cz,isz,rr,ri)
// read as ds_read_b128 (LDS-pipe cost ~2.6 reads/survivor-wave vs ~6-9 b32),
// plus a wave-uniform x-prefilter (wave w owns x-rows [4w,4w+4)).
// Register accumulators, predicated z-unroll; each voxel written once.
// ---------------------------------------------------------------------------
__global__ __launch_bounds__(256) void tile_accum_kernel(
        const int* __restrict__ cnt, const int* __restrict__ off,
        const int* __restrict__ ciA,
        const float* __restrict__ czA, const float* __restrict__ cxA,
        const float* __restrict__ cyA,
        const float* __restrict__ iszA, const float* __restrict__ isxA,
        const float* __restrict__ isyA,
        const float* __restrict__ rrA, const float* __restrict__ riA,
        float2* __restrict__ cvol, float* __restrict__ out_vr) {
    __shared__ int    sci[CAP];
    __shared__ float4 srA[CAP];      // cx, cy, isx, isy
    __shared__ float4 srB[CAP];      // cz, isz, rr, ri
    __shared__ int wcnt[4];

    int tile = blockIdx.x;           // tz*256 + tx*16 + ty ; tz in [0,16)
    int ty = tile & 15, tx = (tile >> 4) & 15, tz = tile >> 8;
    int z0 = tz << 3, x0 = tx << 4, y0 = ty << 4;
    int t = threadIdx.x;
    int lane = t & 63, wid = t >> 6;
    int yl = t & 15, xl = t >> 4;
    int nx = x0 + xl, ny = y0 + yl;
    float nxf = (float)nx * (2.0f / 255.0f) - 1.0f;
    float nyf = (float)ny * (2.0f / 255.0f) - 1.0f;
    int wxlo = x0 + (wid << 2);      // wave owns x-rows [wxlo, wxlo+3]
    int wxhi = wxlo + 3;

    float accR[8], accI[8], zfs[8];
    #pragma unroll
    for (int i = 0; i < 8; i++) {
        accR[i] = 0.f; accI[i] = 0.f;
        zfs[i] = (float)(z0 + i) * (2.0f / 127.0f) - 1.0f;
    }

    int bzl = max(z0 - 3, 0) >> 4,  bzh = min(z0 + 10, 127) >> 4;  // <=2 bins
    int bxl = max(x0 - 3, 0) >> 4,  bxh = min(x0 + 18, 255) >> 4;  // <=3 bins
    int byl = max(y0 - 3, 0) >> 4,  byh = min(y0 + 18, 255) >> 4;

    // ---- build <=6 flattened ranges as scalar registers (no arrays) ----
#define MKRANGE(slot, BZ, BX, VALID)                                          \
    int qs##slot = 0, len##slot = 0;                                          \
    if (VALID) {                                                              \
        int bl_ = ((BZ) << 8) | ((BX) << 4) | byl;                            \
        int bh_ = ((BZ) << 8) | ((BX) << 4) | byh;                            \
        qs##slot = off[bl_];                                                  \
        len##slot = off[bh_] + cnt[bh_] - qs##slot;                           \
    }
    bool hz1 = (bzh > bzl);
    bool hx1 = (bxh >= bxl + 1), hx2 = (bxh >= bxl + 2);
    MKRANGE(0, bzl,     bxl,     true)
    MKRANGE(1, bzl,     bxl + 1, hx1)
    MKRANGE(2, bzl,     bxl + 2, hx2)
    MKRANGE(3, bzl + 1, bxl,     hz1)
    MKRANGE(4, bzl + 1, bxl + 1, hz1 && hx1)
    MKRANGE(5, bzl + 1, bxl + 2, hz1 && hx2)
#undef MKRANGE
    int cum1 = len0;
    int cum2 = cum1 + len1;
    int cum3 = cum2 + len2;
    int cum4 = cum3 + len3;
    int cum5 = cum4 + len4;
    int T    = cum5 + len5;

// process the lc-entry LDS list (packed records, wave x-prefilter)
#define PROCESS_LIST()                                                        \
    for (int u = 0; u < lc; u++) {                                            \
        int cp = sci[u];                                                      \
        int ix = (cp >> 8) & 255;                                             \
        if (ix + 3 < wxlo || ix - 3 > wxhi) continue;   /* wave-uniform */    \
        int iz = cp >> 16, iy = cp & 255;                                     \
        int dxi = nx - ix, dyi = ny - iy;                                     \
        bool colok = (dxi >= -3 && dxi <= 3 && dyi >= -3 && dyi <= 3);        \
        float4 rA = srA[u];                                                   \
        float dxv = (nxf - rA.x) * rA.z;                                      \
        float dyv = (nyf - rA.y) * rA.w;                                      \
        float dxy2 = dxv * dxv + dyv * dyv;                                   \
        if (!colok || dxy2 > 9.0f) continue;                                  \
        float4 rB = srB[u];                                                   \
        int zlo = max(z0, iz - 3) - z0;                                       \
        int zhi = min(z0 + 7, iz + 3) - z0;                                   \
        _Pragma("unroll")                                                     \
        for (int zl = 0; zl < 8; zl++) {                                      \
            if (zl >= zlo && zl <= zhi) {                                     \
                float dzv = (zfs[zl] - rB.x) * rB.y;                          \
                float d2 = dxy2 + dzv * dzv;                                  \
                if (d2 <= 9.0f) {                                             \
                    float w = __expf(-0.5f * d2);                             \
                    accR[zl] += rB.z * w;                                     \
                    accI[zl] += rB.w * w;                                     \
                }                                                             \
            }                                                                 \
        }                                                                     \
    }

    int lc = 0;                      // uniform register list count
    for (int f0 = 0; f0 < T; f0 += 256) {
        // ---- cull + record load over the flattened index space ----
        int f = f0 + t;
        bool keep = false;
        int cpv = 0;
        float czv, cxv, cyv, iszv, isxv, isyv, rrv, riv;
        if (f < T) {
            int q = qs0 + f;
            if (f >= cum1) q = qs1 + (f - cum1);
            if (f >= cum2) q = qs2 + (f - cum2);
            if (f >= cum3) q = qs3 + (f - cum3);
            if (f >= cum4) q = qs4 + (f - cum4);
            if (f >= cum5) q = qs5 + (f - cum5);
            cpv = ciA[q];
            int iz = cpv >> 16, ix = (cpv >> 8) & 255, iy = cpv & 255;
            keep = !(ix + 3 < x0 || ix > x0 + 18 ||
                     iy + 3 < y0 || iy > y0 + 18 ||
                     iz + 3 < z0 || iz > z0 + 10);
            if (keep) {
                czv = czA[q]; cxv = cxA[q]; cyv = cyA[q];
                iszv = iszA[q]; isxv = isxA[q]; isyv = isyA[q];
                rrv = rrA[q]; riv = riA[q];
            }
        }
        unsigned long long m = __ballot(keep);
        __syncthreads();               // protect wcnt from prior read
        if (lane == 0) wcnt[wid] = __popcll(m);
        __syncthreads();               // wcnt + prior record writes visible
        int ntot = wcnt[0] + wcnt[1] + wcnt[2] + wcnt[3];
        if (lc + ntot > CAP) {
            PROCESS_LIST()
            __syncthreads();           // done reading before overwrite
            lc = 0;
        }
        int basew = lc;
        #pragma unroll
        for (int w = 0; w < 4; w++) if (w < wid) basew += wcnt[w];
        if (keep) {
            int pos = basew + __popcll(m & ((1ULL << lane) - 1));
            sci[pos] = cpv;
            srA[pos] = make_float4(cxv, cyv, isxv, isyv);
            srB[pos] = make_float4(czv, iszv, rrv, riv);
        }
        lc += ntot;
    }
    __syncthreads();                 // last record writes visible
    PROCESS_LIST()
#undef PROCESS_LIST

    #pragma unroll
    for (int zl = 0; zl < 8; zl++) {
        size_t idx = ((size_t)(z0 + zl) * NXd + nx) * NYd + ny;
        cvol[idx] = make_float2(accR[zl], accI[zl]);
        out_vr[idx] = accR[zl];
    }
}

// ---------------------------------------------------------------------------
// Legacy in-LDS radix-2 FFT (interleaved fallback only).
// ---------------------------------------------------------------------------
template <int L>
__device__ __forceinline__ void fft_lds(float2* buf) {
    int tid = threadIdx.x;
    for (int half = 1; half < L; half <<= 1) {
        __syncthreads();
        int j = tid & (half - 1);
        int i0 = ((tid ^ j) << 1) | j;
        int i1 = i0 + half;
        float ang = -PI_F * (float)j / (float)half;
        float s, c;
        sincosf(ang, &s, &c);
        float2 a = buf[i0];
        float2 b = buf[i1];
        float tr = c * b.x - s * b.y;
        float ti = c * b.y + s * b.x;
        buf[i0] = make_float2(a.x + tr, a.y + ti);
        buf[i1] = make_float2(a.x - tr, a.y - ti);
    }
    __syncthreads();
}

// Pass 1 (Y, contiguous, len 256): two lines per block, 256 threads.
// Input phase (-1)^(z+x+y) folded in; one shared twiddle table.
__global__ __launch_bounds__(256) void fft_y2_kernel(const float2* __restrict__ src,
                                                     float2* __restrict__ dst) {
    __shared__ float2 buf[2][256];
    __shared__ float2 tw[128];
    int t = threadIdx.x;
    int li = t >> 7;                  // 0 or 1
    int tid = t & 127;
    int l = (blockIdx.x << 1) + li;   // l = z*NX + x
    if (t < 128) {
        float s, c;
        sincosf(-PI_F * (float)t / 128.0f, &s, &c);
        tw[t] = make_float2(c, s);
    }
    int p = ((l >> 8) + l) & 1;       // parity of z + x
    const float2* s = src + (size_t)l * NYd;
    for (int i = tid; i < 256; i += 128) {
        float2 v = s[i];
        if ((p + i) & 1) { v.x = -v.x; v.y = -v.y; }
        buf[li][__brev((unsigned)i) >> 24] = v;
    }
    #pragma unroll
    for (int st = 0; st < 8; st++) {
        const int half = 1 << st;
        const int twstep = 128 >> st;
        __syncthreads();
        int j = tid & (half - 1);
        int i0 = ((tid ^ j) << 1) | j;
        int i1 = i0 + half;
        float2 w = tw[j * twstep];
        float2 a = buf[li][i0];
        float2 b = buf[li][i1];
        float tr = w.x * b.x - w.y * b.y;
        float ti = w.x * b.y + w.y * b.x;
        buf[li][i0] = make_float2(a.x + tr, a.y + ti);
        buf[li][i1] = make_float2(a.x - tr, a.y - ti);
    }
    __syncthreads();
    float2* d = dst + (size_t)l * NYd;
    for (int i = tid; i < 256; i += 128) d[i] = buf[li][i];
}

// Legacy single-line Y / X / Z passes (interleaved fallback only).
__global__ void fft_y_kernel(const float2* __restrict__ src,
                             float2* __restrict__ dst) {
    __shared__ float2 buf[256];
    int l = blockIdx.x;
    int tid = threadIdx.x;
    int p = ((l >> 8) + l) & 1;
    const float2* s = src + (size_t)l * NYd;
    for (int i = tid; i < 256; i += 128) {
        float2 v = s[i];
        if ((p + i) & 1) { v.x = -v.x; v.y = -v.y; }
        buf[__brev((unsigned)i) >> 24] = v;
    }
    fft_lds<256>(buf);
    float2* d = dst + (size_t)l * NYd;
    for (int i = tid; i < 256; i += 128) d[i] = buf[i];
}
__global__ void fft_x_kernel(float2* __restrict__ ks) {
    __shared__ float2 buf[256];
    int l = blockIdx.x;
    int tid = threadIdx.x;
    int z = l >> 8, y = l & 255;
    float2* base = ks + (size_t)z * (NXd * NYd) + y;
    for (int i = tid; i < 256; i += 128)
        buf[__brev((unsigned)i) >> 24] = base[(size_t)i * NYd];
    fft_lds<256>(buf);
    for (int i = tid; i < 256; i += 128)
        base[(size_t)i * NYd] = buf[i];
}
__global__ void fft_z_kernel(float2* __restrict__ ks,
                             const float* __restrict__ mask,
                             float* __restrict__ out_real) {
    __shared__ float2 buf[128];
    int l = blockIdx.x;
    int tid = threadIdx.x;
    float2* base = ks + l;
    for (int i = tid; i < 128; i += 64)
        buf[__brev((unsigned)i) >> 25] = base[(size_t)i * (NXd * NYd)];
    fft_lds<128>(buf);
    int p = ((l >> 8) + l) & 1;
    for (int i = tid; i < 128; i += 64) {
        float2 v = buf[i];
        float sgn = ((p + i) & 1) ? -SCALE_ORTHO : SCALE_ORTHO;
        float m = mask[(size_t)i * (NXd * NYd) + l] * sgn;
        if (out_real) {
            out_real[(size_t)i * (NXd * NYd) + l] = v.x * m;
        } else {
            v.x *= m; v.y *= m;
            base[(size_t)i * (NXd * NYd)] = v;
        }
    }
}

// ---------------------------------------------------------------------------
// Batched X pass: 16 lines (adjacent y) of length 256 per block, 256 threads.
// ---------------------------------------------------------------------------
__global__ __launch_bounds__(256) void fft_x16_kernel(float2* __restrict__ ks) {
    __shared__ float2 buf[16][256 + 1];
    __shared__ float2 tw[128];
    int t = threadIdx.x;
    int blk = blockIdx.x;            // z*16 + y_group
    int z = blk >> 4;
    int y16 = (blk & 15) << 4;
    if (t < 128) {
        float s, c;
        sincosf(-PI_F * (float)t / 128.0f, &s, &c);
        tw[t] = make_float2(c, s);
    }
    float2* base = ks + (size_t)z * (NXd * NYd) + y16;
    int yl = t & 15, xe0 = t >> 4;   // 16 y x 16 x per pass
    #pragma unroll
    for (int p = 0; p < 16; p++) {
        int xe = xe0 + (p << 4);
        float2 v = base[(size_t)xe * NYd + yl];
        buf[yl][__brev((unsigned)xe) >> 24] = v;
    }
    int s_ = t & 127;
    int fb0 = t >> 7;                // 0..1; lines fb0 + 2u
    #pragma unroll
    for (int st = 0; st < 8; st++) {
        const int half = 1 << st;
        const int twstep = 128 >> st;
        __syncthreads();
        int j = s_ & (half - 1);
        int i0 = ((s_ ^ j) << 1) | j;
        int i1 = i0 + half;
        float2 w = tw[j * twstep];
        #pragma unroll
        for (int u = 0; u < 8; u++) {
            int fb = fb0 + (u << 1);
            float2 a = buf[fb][i0];
            float2 b = buf[fb][i1];
            float tr = w.x * b.x - w.y * b.y;
            float ti = w.x * b.y + w.y * b.x;
            buf[fb][i0] = make_float2(a.x + tr, a.y + ti);
            buf[fb][i1] = make_float2(a.x - tr, a.y - ti);
        }
    }
    __syncthreads();
    #pragma unroll
    for (int p = 0; p < 16; p++) {
        int xe = xe0 + (p << 4);
        base[(size_t)xe * NYd + yl] = buf[yl][xe];
    }
}

// ---------------------------------------------------------------------------
// Batched Z pass: 32 lines (adjacent ky) of length 128 per block, 256 thr.
// 256 B load chunks / 128 B store chunks; fused phase, scale, mask, real out.
// ---------------------------------------------------------------------------
__global__ __launch_bounds__(256) void fft_z32_kernel(const float2* __restrict__ ks,
                                                      const float* __restrict__ mask,
                                                      float* __restrict__ out_kr) {
    __shared__ float2 buf[32][128 + 1];
    __shared__ float2 tw[64];
    int t = threadIdx.x;
    int blk = blockIdx.x;            // kx*8 + ky_group
    int kx = blk >> 3;
    int ky32 = (blk & 7) << 5;
    if (t < 64) {
        float s, c;
        sincosf(-PI_F * (float)t / 64.0f, &s, &c);
        tw[t] = make_float2(c, s);
    }
    const float2* base = ks + (size_t)kx * NYd + ky32;
    int kyl = t & 31, ze0 = t >> 5;  // 32 y x 8 z per pass
    #pragma unroll
    for (int p = 0; p < 16; p++) {
        int ze = ze0 + (p << 3);
        float2 v = base[(size_t)ze * (NXd * NYd) + kyl];
        buf[kyl][__brev((unsigned)ze) >> 25] = v;
    }
    int s_ = t & 63;
    int fb0 = t >> 6;                // 0..3; lines fb0 + 4u
    #pragma unroll
    for (int st = 0; st < 7; st++) {
        const int half = 1 << st;
        const int twstep = 64 >> st;
        __syncthreads();
        int j = s_ & (half - 1);
        int i0 = ((s_ ^ j) << 1) | j;
        int i1 = i0 + half;
        float2 w = tw[j * twstep];
        #pragma unroll
        for (int u = 0; u < 8; u++) {
            int fb = fb0 + (u << 2);
            float2 a = buf[fb][i0];
            float2 b = buf[fb][i1];
            float tr = w.x * b.x - w.y * b.y;
            float ti = w.x * b.y + w.y * b.x;
            buf[fb][i0] = make_float2(a.x + tr, a.y + ti);
            buf[fb][i1] = make_float2(a.x - tr, a.y - ti);
        }
    }
    __syncthreads();
    int ky = ky32 + kyl;
    #pragma unroll
    for (int p = 0; p < 16; p++) {
        int ze = ze0 + (p << 3);
        float2 v = buf[kyl][ze];
        size_t gi = (size_t)ze * (NXd * NYd) + (size_t)kx * NYd + ky;
        float sgn = ((ze + kx + ky) & 1) ? -SCALE_ORTHO : SCALE_ORTHO;
        out_kr[gi] = v.x * (mask[gi] * sgn);
    }
}

// ---------------------------------------------------------------------------
extern "C" void kernel_launch(void* const* d_in, const int* in_sizes, int n_in,
                              void* d_out, int out_size, void* d_ws, size_t ws_size,
                              hipStream_t stream) {
    const float* mask       = (const float*)d_in[0];
    const float* centers    = (const float*)d_in[1];
    const float* log_scales = (const float*)d_in[2];
    const float* rho_r      = (const float*)d_in[3];
    const float* rho_i      = (const float*)d_in[4];
    int M = in_sizes[1] / 3;          // 50000

    bool inter = (out_size >= 4 * NVOX);
    if (!inter) {
        // real-output layout (proven in round 5): d_out = [vol_real | ks_real]
        if (out_size < 2 * NVOX || ws_size < (size_t)NVOX * 8) {
            int z4 = out_size / 4;
            if (z4 > 0)
                zero_kernel<<<(z4 + 255) / 256, 256, 0, stream>>>((float4*)d_out, z4);
            return;
        }
        float* out_vr = (float*)d_out;
        float* out_kr = out_vr + NVOX;
        float2* cvol = (float2*)d_ws;

        int Mpad = (M + 63) & ~63;
        bool fast = (8192 + 9LL * Mpad) <= (long long)NVOX;  // scratch fits in ks half
        if (fast) {
            int* ibase  = (int*)out_kr;      // dead before fft_z32 overwrites region
            int* cnt    = ibase;
            int* off    = ibase + 2048;
            int* cursor = ibase + 4096;
            float* fbase = (float*)(ibase + 8192);
            int*   ciA  = (int*)fbase;
            float* czA  = fbase + 1LL * Mpad;
            float* cxA  = fbase + 2LL * Mpad;
            float* cyA  = fbase + 3LL * Mpad;
            float* iszA = fbase + 4LL * Mpad;
            float* isxA = fbase + 5LL * Mpad;
            float* isyA = fbase + 6LL * Mpad;
            float* rrA  = fbase + 7LL * Mpad;
            float* riA  = fbase + 8LL * Mpad;

            hipMemsetAsync(cnt, 0, 2048 * sizeof(int), stream);
            bin_count_kernel<<<(M + 255) / 256, 256, 0, stream>>>(centers, cnt, M);
            bin_scan_kernel<<<1, 64, 0, stream>>>(cnt, off, cursor);
            bin_scatter_kernel<<<(M + 255) / 256, 256, 0, stream>>>(
                centers, log_scales, rho_r, rho_i, cursor,
                ciA, czA, cxA, cyA, iszA, isxA, isyA, rrA, riA, M);
            tile_accum_kernel<<<4096, 256, 0, stream>>>(
                cnt, off, ciA, czA, cxA, cyA, iszA, isxA, isyA, rrA, riA,
                cvol, out_vr);
        } else {
            // fallback: atomic voxelize
            int n4 = (2 * NVOX) / 4;
            zero_kernel<<<(n4 + 255) / 256, 256, 0, stream>>>((float4*)cvol, n4);
            long long total = (long long)M * 343;
            int vb = (int)((total + 255) / 256);
            voxelize_kernel<<<vb, 256, 0, stream>>>(centers, log_scales, rho_r,
                                                    rho_i, (float*)cvol, M);
            copy_real_kernel<<<NVOX / 256, 256, 0, stream>>>(cvol, out_vr);
        }

        // centered ortho 3D FFT (shift trick) + mask, real store
        fft_y2_kernel<<<NZd * NXd / 2, 256, 0, stream>>>(cvol, cvol);
        fft_x16_kernel<<<NZd * 16, 256, 0, stream>>>(cvol);
        fft_z32_kernel<<<NXd * 8, 256, 0, stream>>>(cvol, mask, out_kr);
    } else {
        // legacy interleaved-complex layout (unused in practice, kept safe)
        float2* cvol = (float2*)d_out;
        float2* cks  = cvol + NVOX;
        int n4 = (2 * NVOX) / 4;
        zero_kernel<<<(n4 + 255) / 256, 256, 0, stream>>>((float4*)cvol, n4);
        long long total = (long long)M * 343;
        int vb = (int)((total + 255) / 256);
        voxelize_kernel<<<vb, 256, 0, stream>>>(centers, log_scales, rho_r,
                                                rho_i, (float*)cvol, M);
        fft_y_kernel<<<NZd * NXd, 128, 0, stream>>>(cvol, cks);
        fft_x_kernel<<<NZd * NYd, 128, 0, stream>>>(cks);
        fft_z_kernel<<<NXd * NYd, 64, 0, stream>>>(cks, mask, nullptr);
    }
}

// Round 17
// 195.344 us; speedup vs baseline: 1.0218x; 1.0218x over previous
//
#include <hip/hip_runtime.h>
#include <math.h>

#define NZd 128
#define NXd 256
#define NYd 256
#define NVOX (NZd * NXd * NYd)   // 8,388,608 voxels
#define PI_F 3.14159265358979323846f
#define SCALE_ORTHO 3.4526698300124393e-4f  // 1/sqrt(128*256*256)
#define CAP 512                  // LDS survivor-list capacity

// ---------------------------------------------------------------------------
// Zero helper (guard path only).
// ---------------------------------------------------------------------------
__global__ void zero_kernel(float4* __restrict__ p, int n4) {
    int i = blockIdx.x * blockDim.x + threadIdx.x;
    if (i < n4) p[i] = make_float4(0.f, 0.f, 0.f, 0.f);
}

// ---------------------------------------------------------------------------
// Legacy atomic voxelize (fallback / interleaved path only).
// ---------------------------------------------------------------------------
__global__ void voxelize_kernel(const float* __restrict__ centers,
                                const float* __restrict__ log_scales,
                                const float* __restrict__ rho_r,
                                const float* __restrict__ rho_i,
                                float* __restrict__ vol, int M) {
    long long t = (long long)blockIdx.x * blockDim.x + threadIdx.x;
    if (t >= (long long)M * 343) return;
    int g = (int)(t / 343);
    int k = (int)(t % 343);
    int oz = k / 49 - 3, ox = (k / 7) % 7 - 3, oy = k % 7 - 3;
    float cz = centers[g * 3 + 0], cx = centers[g * 3 + 1], cy = centers[g * 3 + 2];
    int iz = (int)rintf((cz + 1.0f) * 0.5f * 127.0f);
    int ix = (int)rintf((cx + 1.0f) * 0.5f * 255.0f);
    int iy = (int)rintf((cy + 1.0f) * 0.5f * 255.0f);
    int nz = iz + oz, nx = ix + ox, ny = iy + oy;
    if (nz < 0 || nz >= NZd || nx < 0 || nx >= NXd || ny < 0 || ny >= NYd) return;
    float sz = expf(log_scales[g * 3 + 0]) + 1e-8f;
    float sx = expf(log_scales[g * 3 + 1]) + 1e-8f;
    float sy = expf(log_scales[g * 3 + 2]) + 1e-8f;
    float dz = ((float)nz / 127.0f * 2.0f - 1.0f - cz) / sz;
    float dx = ((float)nx / 255.0f * 2.0f - 1.0f - cx) / sx;
    float dy = ((float)ny / 255.0f * 2.0f - 1.0f - cy) / sy;
    float d2 = dz * dz + dx * dx + dy * dy;
    if (d2 > 9.0f) return;
    float w = expf(-0.5f * d2);
    int idx = (nz * NXd + nx) * NYd + ny;
    atomicAdd(&vol[2 * idx + 0], rho_r[g] * w);
    atomicAdd(&vol[2 * idx + 1], rho_i[g] * w);
}

__global__ void copy_real_kernel(const float2* __restrict__ cvol,
                                 float* __restrict__ out) {
    int i = blockIdx.x * blockDim.x + threadIdx.x;
    out[i] = cvol[i].x;
}

// ---------------------------------------------------------------------------
// Binning: count -> scan -> scatter precomputed gaussian records.
// Bin = 16^3 cell of the nearest-voxel center: 8 x 16 x 16 = 2048 bins.
// ---------------------------------------------------------------------------
__device__ __forceinline__ void center_voxel(const float* __restrict__ centers,
                                             int g, int& iz, int& ix, int& iy) {
    float cz = centers[g * 3 + 0], cx = centers[g * 3 + 1], cy = centers[g * 3 + 2];
    iz = min(max((int)rintf((cz + 1.0f) * 0.5f * 127.0f), 0), 127);
    ix = min(max((int)rintf((cx + 1.0f) * 0.5f * 255.0f), 0), 255);
    iy = min(max((int)rintf((cy + 1.0f) * 0.5f * 255.0f), 0), 255);
}

__global__ void bin_count_kernel(const float* __restrict__ centers,
                                 int* __restrict__ cnt, int M) {
    int g = blockIdx.x * blockDim.x + threadIdx.x;
    if (g >= M) return;
    int iz, ix, iy;
    center_voxel(centers, g, iz, ix, iy);
    atomicAdd(&cnt[((iz >> 4) << 8) | ((ix >> 4) << 4) | (iy >> 4)], 1);
}

// one wave scans 2048 counts -> exclusive offsets (+ cursor copy)
__global__ void bin_scan_kernel(const int* __restrict__ cnt,
                                int* __restrict__ off,
                                int* __restrict__ cursor) {
    int lane = threadIdx.x;      // 64 threads
    int base = lane << 5;        // 32 bins per lane
    int s = 0;
    #pragma unroll
    for (int i = 0; i < 32; i++) s += cnt[base + i];
    int incl = s;
    #pragma unroll
    for (int d = 1; d < 64; d <<= 1) {
        int v = __shfl_up(incl, d, 64);
        if (lane >= d) incl += v;
    }
    int run = incl - s;          // exclusive prefix of this lane's chunk
    for (int i = 0; i < 32; i++) {
        int c = cnt[base + i];
        off[base + i] = run;
        cursor[base + i] = run;
        run += c;
    }
}

__global__ void bin_scatter_kernel(const float* __restrict__ centers,
                                   const float* __restrict__ log_scales,
                                   const float* __restrict__ rho_r,
                                   const float* __restrict__ rho_i,
                                   int* __restrict__ cursor,
                                   int* __restrict__ ciA,
                                   float* __restrict__ czA, float* __restrict__ cxA,
                                   float* __restrict__ cyA,
                                   float* __restrict__ iszA, float* __restrict__ isxA,
                                   float* __restrict__ isyA,
                                   float* __restrict__ rrA, float* __restrict__ riA,
                                   int M) {
    int g = blockIdx.x * blockDim.x + threadIdx.x;
    if (g >= M) return;
    int iz, ix, iy;
    center_voxel(centers, g, iz, ix, iy);
    int b = ((iz >> 4) << 8) | ((ix >> 4) << 4) | (iy >> 4);
    int pos = atomicAdd(&cursor[b], 1);
    ciA[pos] = (iz << 16) | (ix << 8) | iy;
    czA[pos] = centers[g * 3 + 0];
    cxA[pos] = centers[g * 3 + 1];
    cyA[pos] = centers[g * 3 + 2];
    iszA[pos] = 1.0f / (expf(log_scales[g * 3 + 0]) + 1e-8f);
    isxA[pos] = 1.0f / (expf(log_scales[g * 3 + 1]) + 1e-8f);
    isyA[pos] = 1.0f / (expf(log_scales[g * 3 + 2]) + 1e-8f);
    rrA[pos] = rho_r[g];
    riA[pos] = rho_i[g];
}

// ---------------------------------------------------------------------------
// Tile accumulation, 16x16x8 tiles (4096 blocks): round-14 proven structure
// (flattened cull, ballot-compacted scalar LDS records, column-parallel
// process with predicated z-unroll + register accumulators).
// __launch_bounds__(256, 8): request 8 waves/EU (= 8 blocks/CU) residency —
// static limits allow it (18.9 KB LDS, 36 VGPR) but measured occupancy was
// only 49% without the hint.
// ---------------------------------------------------------------------------
__global__ __launch_bounds__(256, 8) void tile_accum_kernel(
        const int* __restrict__ cnt, const int* __restrict__ off,
        const int* __restrict__ ciA,
        const float* __restrict__ czA, const float* __restrict__ cxA,
        const float* __restrict__ cyA,
        const float* __restrict__ iszA, const float* __restrict__ isxA,
        const float* __restrict__ isyA,
        const float* __restrict__ rrA, const float* __restrict__ riA,
        float2* __restrict__ cvol, float* __restrict__ out_vr) {
    __shared__ int   sci[CAP];
    __shared__ float scz[CAP], scx[CAP], scy[CAP];
    __shared__ float sisz[CAP], sisx[CAP], sisy[CAP];
    __shared__ float srr[CAP], sri[CAP];               // 18.4 KB
    __shared__ int wcnt[4];

    int tile = blockIdx.x;           // tz*256 + tx*16 + ty ; tz in [0,16)
    int ty = tile & 15, tx = (tile >> 4) & 15, tz = tile >> 8;
    int z0 = tz << 3, x0 = tx << 4, y0 = ty << 4;
    int t = threadIdx.x;
    int lane = t & 63, wid = t >> 6;
    int yl = t & 15, xl = t >> 4;
    int nx = x0 + xl, ny = y0 + yl;
    float nxf = (float)nx * (2.0f / 255.0f) - 1.0f;
    float nyf = (float)ny * (2.0f / 255.0f) - 1.0f;

    float accR[8], accI[8], zfs[8];
    #pragma unroll
    for (int i = 0; i < 8; i++) {
        accR[i] = 0.f; accI[i] = 0.f;
        zfs[i] = (float)(z0 + i) * (2.0f / 127.0f) - 1.0f;
    }

    int bzl = max(z0 - 3, 0) >> 4,  bzh = min(z0 + 10, 127) >> 4;  // <=2 bins
    int bxl = max(x0 - 3, 0) >> 4,  bxh = min(x0 + 18, 255) >> 4;  // <=3 bins
    int byl = max(y0 - 3, 0) >> 4,  byh = min(y0 + 18, 255) >> 4;

    // ---- build <=6 flattened ranges as scalar registers (no arrays) ----
#define MKRANGE(slot, BZ, BX, VALID)                                          \
    int qs##slot = 0, len##slot = 0;                                          \
    if (VALID) {                                                              \
        int bl_ = ((BZ) << 8) | ((BX) << 4) | byl;                            \
        int bh_ = ((BZ) << 8) | ((BX) << 4) | byh;                            \
        qs##slot = off[bl_];                                                  \
        len##slot = off[bh_] + cnt[bh_] - qs##slot;                           \
    }
    bool hz1 = (bzh > bzl);
    bool hx1 = (bxh >= bxl + 1), hx2 = (bxh >= bxl + 2);
    MKRANGE(0, bzl,     bxl,     true)
    MKRANGE(1, bzl,     bxl + 1, hx1)
    MKRANGE(2, bzl,     bxl + 2, hx2)
    MKRANGE(3, bzl + 1, bxl,     hz1)
    MKRANGE(4, bzl + 1, bxl + 1, hz1 && hx1)
    MKRANGE(5, bzl + 1, bxl + 2, hz1 && hx2)
#undef MKRANGE
    int cum1 = len0;
    int cum2 = cum1 + len1;
    int cum3 = cum2 + len2;
    int cum4 = cum3 + len3;
    int cum5 = cum4 + len4;
    int T    = cum5 + len5;

// process the lc-entry LDS list (round-14 structure)
#define PROCESS_LIST()                                                        \
    for (int u = 0; u < lc; u++) {                                            \
        int cp = sci[u];                                                      \
        int iz = cp >> 16, ix = (cp >> 8) & 255, iy = cp & 255;               \
        int dxi = nx - ix, dyi = ny - iy;                                     \
        if (dxi < -3 || dxi > 3 || dyi < -3 || dyi > 3) continue;             \
        float dxv = (nxf - scx[u]) * sisx[u];                                 \
        float dyv = (nyf - scy[u]) * sisy[u];                                 \
        float dxy2 = dxv * dxv + dyv * dyv;                                   \
        if (dxy2 > 9.0f) continue;                                            \
        float cz_ = scz[u], isz_ = sisz[u];                                   \
        float rr = srr[u], ri = sri[u];                                       \
        int zlo = max(z0, iz - 3) - z0;                                       \
        int zhi = min(z0 + 7, iz + 3) - z0;                                   \
        _Pragma("unroll")                                                     \
        for (int zl = 0; zl < 8; zl++) {                                      \
            if (zl >= zlo && zl <= zhi) {                                     \
                float dzv = (zfs[zl] - cz_) * isz_;                           \
                float d2 = dxy2 + dzv * dzv;                                  \
                if (d2 <= 9.0f) {                                             \
                    float w = __expf(-0.5f * d2);                             \
                    accR[zl] += rr * w;                                       \
                    accI[zl] += ri * w;                                       \
                }                                                             \
            }                                                                 \
        }                                                                     \
    }

    int lc = 0;                      // uniform register list count
    for (int f0 = 0; f0 < T; f0 += 256) {
        // ---- cull + record load over the flattened index space ----
        int f = f0 + t;
        bool keep = false;
        int cpv = 0;
        float czv, cxv, cyv, iszv, isxv, isyv, rrv, riv;
        if (f < T) {
            int q = qs0 + f;
            if (f >= cum1) q = qs1 + (f - cum1);
            if (f >= cum2) q = qs2 + (f - cum2);
            if (f >= cum3) q = qs3 + (f - cum3);
            if (f >= cum4) q = qs4 + (f - cum4);
            if (f >= cum5) q = qs5 + (f - cum5);
            cpv = ciA[q];
            int iz = cpv >> 16, ix = (cpv >> 8) & 255, iy = cpv & 255;
            keep = !(ix + 3 < x0 || ix > x0 + 18 ||
                     iy + 3 < y0 || iy > y0 + 18 ||
                     iz + 3 < z0 || iz > z0 + 10);
            if (keep) {
                czv = czA[q]; cxv = cxA[q]; cyv = cyA[q];
                iszv = iszA[q]; isxv = isxA[q]; isyv = isyA[q];
                rrv = rrA[q]; riv = riA[q];
            }
        }
        unsigned long long m = __ballot(keep);
        __syncthreads();               // protect wcnt from prior read
        if (lane == 0) wcnt[wid] = __popcll(m);
        __syncthreads();               // wcnt + prior record writes visible
        int ntot = wcnt[0] + wcnt[1] + wcnt[2] + wcnt[3];
        if (lc + ntot > CAP) {
            PROCESS_LIST()
            __syncthreads();           // done reading before overwrite
            lc = 0;
        }
        int basew = lc;
        #pragma unroll
        for (int w = 0; w < 4; w++) if (w < wid) basew += wcnt[w];
        if (keep) {
            int pos = basew + __popcll(m & ((1ULL << lane) - 1));
            sci[pos] = cpv;
            scz[pos] = czv; scx[pos] = cxv; scy[pos] = cyv;
            sisz[pos] = iszv; sisx[pos] = isxv; sisy[pos] = isyv;
            srr[pos] = rrv; sri[pos] = riv;
        }
        lc += ntot;
    }
    __syncthreads();                 // last record writes visible
    PROCESS_LIST()
#undef PROCESS_LIST

    #pragma unroll
    for (int zl = 0; zl < 8; zl++) {
        size_t idx = ((size_t)(z0 + zl) * NXd + nx) * NYd + ny;
        cvol[idx] = make_float2(accR[zl], accI[zl]);
        out_vr[idx] = accR[zl];
    }
}

// ---------------------------------------------------------------------------
// Legacy in-LDS radix-2 FFT (interleaved fallback only).
// ---------------------------------------------------------------------------
template <int L>
__device__ __forceinline__ void fft_lds(float2* buf) {
    int tid = threadIdx.x;
    for (int half = 1; half < L; half <<= 1) {
        __syncthreads();
        int j = tid & (half - 1);
        int i0 = ((tid ^ j) << 1) | j;
        int i1 = i0 + half;
        float ang = -PI_F * (float)j / (float)half;
        float s, c;
        sincosf(ang, &s, &c);
        float2 a = buf[i0];
        float2 b = buf[i1];
        float tr = c * b.x - s * b.y;
        float ti = c * b.y + s * b.x;
        buf[i0] = make_float2(a.x + tr, a.y + ti);
        buf[i1] = make_float2(a.x - tr, a.y - ti);
    }
    __syncthreads();
}

// Pass 1 (Y, contiguous, len 256): two lines per block, 256 threads.
// Input phase (-1)^(z+x+y) folded in; one shared twiddle table.
__global__ __launch_bounds__(256) void fft_y2_kernel(const float2* __restrict__ src,
                                                     float2* __restrict__ dst) {
    __shared__ float2 buf[2][256];
    __shared__ float2 tw[128];
    int t = threadIdx.x;
    int li = t >> 7;                  // 0 or 1
    int tid = t & 127;
    int l = (blockIdx.x << 1) + li;   // l = z*NX + x
    if (t < 128) {
        float s, c;
        sincosf(-PI_F * (float)t / 128.0f, &s, &c);
        tw[t] = make_float2(c, s);
    }
    int p = ((l >> 8) + l) & 1;       // parity of z + x
    const float2* s = src + (size_t)l * NYd;
    for (int i = tid; i < 256; i += 128) {
        float2 v = s[i];
        if ((p + i) & 1) { v.x = -v.x; v.y = -v.y; }
        buf[li][__brev((unsigned)i) >> 24] = v;
    }
    #pragma unroll
    for (int st = 0; st < 8; st++) {
        const int half = 1 << st;
        const int twstep = 128 >> st;
        __syncthreads();
        int j = tid & (half - 1);
        int i0 = ((tid ^ j) << 1) | j;
        int i1 = i0 + half;
        float2 w = tw[j * twstep];
        float2 a = buf[li][i0];
        float2 b = buf[li][i1];
        float tr = w.x * b.x - w.y * b.y;
        float ti = w.x * b.y + w.y * b.x;
        buf[li][i0] = make_float2(a.x + tr, a.y + ti);
        buf[li][i1] = make_float2(a.x - tr, a.y - ti);
    }
    __syncthreads();
    float2* d = dst + (size_t)l * NYd;
    for (int i = tid; i < 256; i += 128) d[i] = buf[li][i];
}

// Legacy single-line Y / X / Z passes (interleaved fallback only).
__global__ void fft_y_kernel(const float2* __restrict__ src,
                             float2* __restrict__ dst) {
    __shared__ float2 buf[256];
    int l = blockIdx.x;
    int tid = threadIdx.x;
    int p = ((l >> 8) + l) & 1;
    const float2* s = src + (size_t)l * NYd;
    for (int i = tid; i < 256; i += 128) {
        float2 v = s[i];
        if ((p + i) & 1) { v.x = -v.x; v.y = -v.y; }
        buf[__brev((unsigned)i) >> 24] = v;
    }
    fft_lds<256>(buf);
    float2* d = dst + (size_t)l * NYd;
    for (int i = tid; i < 256; i += 128) d[i] = buf[i];
}
__global__ void fft_x_kernel(float2* __restrict__ ks) {
    __shared__ float2 buf[256];
    int l = blockIdx.x;
    int tid = threadIdx.x;
    int z = l >> 8, y = l & 255;
    float2* base = ks + (size_t)z * (NXd * NYd) + y;
    for (int i = tid; i < 256; i += 128)
        buf[__brev((unsigned)i) >> 24] = base[(size_t)i * NYd];
    fft_lds<256>(buf);
    for (int i = tid; i < 256; i += 128)
        base[(size_t)i * NYd] = buf[i];
}
__global__ void fft_z_kernel(float2* __restrict__ ks,
                             const float* __restrict__ mask,
                             float* __restrict__ out_real) {
    __shared__ float2 buf[128];
    int l = blockIdx.x;
    int tid = threadIdx.x;
    float2* base = ks + l;
    for (int i = tid; i < 128; i += 64)
        buf[__brev((unsigned)i) >> 25] = base[(size_t)i * (NXd * NYd)];
    fft_lds<128>(buf);
    int p = ((l >> 8) + l) & 1;
    for (int i = tid; i < 128; i += 64) {
        float2 v = buf[i];
        float sgn = ((p + i) & 1) ? -SCALE_ORTHO : SCALE_ORTHO;
        float m = mask[(size_t)i * (NXd * NYd) + l] * sgn;
        if (out_real) {
            out_real[(size_t)i * (NXd * NYd) + l] = v.x * m;
        } else {
            v.x *= m; v.y *= m;
            base[(size_t)i * (NXd * NYd)] = v;
        }
    }
}

// ---------------------------------------------------------------------------
// Batched X pass: 16 lines (adjacent y) of length 256 per block, 256 threads.
// ---------------------------------------------------------------------------
__global__ __launch_bounds__(256) void fft_x16_kernel(float2* __restrict__ ks) {
    __shared__ float2 buf[16][256 + 1];
    __shared__ float2 tw[128];
    int t = threadIdx.x;
    int blk = blockIdx.x;            // z*16 + y_group
    int z = blk >> 4;
    int y16 = (blk & 15) << 4;
    if (t < 128) {
        float s, c;
        sincosf(-PI_F * (float)t / 128.0f, &s, &c);
        tw[t] = make_float2(c, s);
    }
    float2* base = ks + (size_t)z * (NXd * NYd) + y16;
    int yl = t & 15, xe0 = t >> 4;   // 16 y x 16 x per pass
    #pragma unroll
    for (int p = 0; p < 16; p++) {
        int xe = xe0 + (p << 4);
        float2 v = base[(size_t)xe * NYd + yl];
        buf[yl][__brev((unsigned)xe) >> 24] = v;
    }
    int s_ = t & 127;
    int fb0 = t >> 7;                // 0..1; lines fb0 + 2u
    #pragma unroll
    for (int st = 0; st < 8; st++) {
        const int half = 1 << st;
        const int twstep = 128 >> st;
        __syncthreads();
        int j = s_ & (half - 1);
        int i0 = ((s_ ^ j) << 1) | j;
        int i1 = i0 + half;
        float2 w = tw[j * twstep];
        #pragma unroll
        for (int u = 0; u < 8; u++) {
            int fb = fb0 + (u << 1);
            float2 a = buf[fb][i0];
            float2 b = buf[fb][i1];
            float tr = w.x * b.x - w.y * b.y;
            float ti = w.x * b.y + w.y * b.x;
            buf[fb][i0] = make_float2(a.x + tr, a.y + ti);
            buf[fb][i1] = make_float2(a.x - tr, a.y - ti);
        }
    }
    __syncthreads();
    #pragma unroll
    for (int p = 0; p < 16; p++) {
        int xe = xe0 + (p << 4);
        base[(size_t)xe * NYd + yl] = buf[yl][xe];
    }
}

// ---------------------------------------------------------------------------
// Batched Z pass: 32 lines (adjacent ky) of length 128 per block, 256 thr.
// 256 B load chunks / 128 B store chunks; fused phase, scale, mask, real out.
// ---------------------------------------------------------------------------
__global__ __launch_bounds__(256) void fft_z32_kernel(const float2* __restrict__ ks,
                                                      const float* __restrict__ mask,
                                                      float* __restrict__ out_kr) {
    __shared__ float2 buf[32][128 + 1];
    __shared__ float2 tw[64];
    int t = threadIdx.x;
    int blk = blockIdx.x;            // kx*8 + ky_group
    int kx = blk >> 3;
    int ky32 = (blk & 7) << 5;
    if (t < 64) {
        float s, c;
        sincosf(-PI_F * (float)t / 64.0f, &s, &c);
        tw[t] = make_float2(c, s);
    }
    const float2* base = ks + (size_t)kx * NYd + ky32;
    int kyl = t & 31, ze0 = t >> 5;  // 32 y x 8 z per pass
    #pragma unroll
    for (int p = 0; p < 16; p++) {
        int ze = ze0 + (p << 3);
        float2 v = base[(size_t)ze * (NXd * NYd) + kyl];
        buf[kyl][__brev((unsigned)ze) >> 25] = v;
    }
    int s_ = t & 63;
    int fb0 = t >> 6;                // 0..3; lines fb0 + 4u
    #pragma unroll
    for (int st = 0; st < 7; st++) {
        const int half = 1 << st;
        const int twstep = 64 >> st;
        __syncthreads();
        int j = s_ & (half - 1);
        int i0 = ((s_ ^ j) << 1) | j;
        int i1 = i0 + half;
        float2 w = tw[j * twstep];
        #pragma unroll
        for (int u = 0; u < 8; u++) {
            int fb = fb0 + (u << 2);
            float2 a = buf[fb][i0];
            float2 b = buf[fb][i1];
            float tr = w.x * b.x - w.y * b.y;
            float ti = w.x * b.y + w.y * b.x;
            buf[fb][i0] = make_float2(a.x + tr, a.y + ti);
            buf[fb][i1] = make_float2(a.x - tr, a.y - ti);
        }
    }
    __syncthreads();
    int ky = ky32 + kyl;
    #pragma unroll
    for (int p = 0; p < 16; p++) {
        int ze = ze0 + (p << 3);
        float2 v = buf[kyl][ze];
        size_t gi = (size_t)ze * (NXd * NYd) + (size_t)kx * NYd + ky;
        float sgn = ((ze + kx + ky) & 1) ? -SCALE_ORTHO : SCALE_ORTHO;
        out_kr[gi] = v.x * (mask[gi] * sgn);
    }
}

// ---------------------------------------------------------------------------
extern "C" void kernel_launch(void* const* d_in, const int* in_sizes, int n_in,
                              void* d_out, int out_size, void* d_ws, size_t ws_size,
                              hipStream_t stream) {
    const float* mask       = (const float*)d_in[0];
    const float* centers    = (const float*)d_in[1];
    const float* log_scales = (const float*)d_in[2];
    const float* rho_r      = (const float*)d_in[3];
    const float* rho_i      = (const float*)d_in[4];
    int M = in_sizes[1] / 3;          // 50000

    bool inter = (out_size >= 4 * NVOX);
    if (!inter) {
        // real-output layout (proven in round 5): d_out = [vol_real | ks_real]
        if (out_size < 2 * NVOX || ws_size < (size_t)NVOX * 8) {
            int z4 = out_size / 4;
            if (z4 > 0)
                zero_kernel<<<(z4 + 255) / 256, 256, 0, stream>>>((float4*)d_out, z4);
            return;
        }
        float* out_vr = (float*)d_out;
        float* out_kr = out_vr + NVOX;
        float2* cvol = (float2*)d_ws;

        int Mpad = (M + 63) & ~63;
        bool fast = (8192 + 9LL * Mpad) <= (long long)NVOX;  // scratch fits in ks half
        if (fast) {
            int* ibase  = (int*)out_kr;      // dead before fft_z32 overwrites region
            int* cnt    = ibase;
            int* off    = ibase + 2048;
            int* cursor = ibase + 4096;
            float* fbase = (float*)(ibase + 8192);
            int*   ciA  = (int*)fbase;
            float* czA  = fbase + 1LL * Mpad;
            float* cxA  = fbase + 2LL * Mpad;
            float* cyA  = fbase + 3LL * Mpad;
            float* iszA = fbase + 4LL * Mpad;
            float* isxA = fbase + 5LL * Mpad;
            float* isyA = fbase + 6LL * Mpad;
            float* rrA  = fbase + 7LL * Mpad;
            float* riA  = fbase + 8LL * Mpad;

            hipMemsetAsync(cnt, 0, 2048 * sizeof(int), stream);
            bin_count_kernel<<<(M + 255) / 256, 256, 0, stream>>>(centers, cnt, M);
            bin_scan_kernel<<<1, 64, 0, stream>>>(cnt, off, cursor);
            bin_scatter_kernel<<<(M + 255) / 256, 256, 0, stream>>>(
                centers, log_scales, rho_r, rho_i, cursor,
                ciA, czA, cxA, cyA, iszA, isxA, isyA, rrA, riA, M);
            tile_accum_kernel<<<4096, 256, 0, stream>>>(
                cnt, off, ciA, czA, cxA, cyA, iszA, isxA, isyA, rrA, riA,
                cvol, out_vr);
        } else {
            // fallback: atomic voxelize
            int n4 = (2 * NVOX) / 4;
            zero_kernel<<<(n4 + 255) / 256, 256, 0, stream>>>((float4*)cvol, n4);
            long long total = (long long)M * 343;
            int vb = (int)((total + 255) / 256);
            voxelize_kernel<<<vb, 256, 0, stream>>>(centers, log_scales, rho_r,
                                                    rho_i, (float*)cvol, M);
            copy_real_kernel<<<NVOX / 256, 256, 0, stream>>>(cvol, out_vr);
        }

        // centered ortho 3D FFT (shift trick) + mask, real store
        fft_y2_kernel<<<NZd * NXd / 2, 256, 0, stream>>>(cvol, cvol);
        fft_x16_kernel<<<NZd * 16, 256, 0, stream>>>(cvol);
        fft_z32_kernel<<<NXd * 8, 256, 0, stream>>>(cvol, mask, out_kr);
    } else {
        // legacy interleaved-complex layout (unused in practice, kept safe)
        float2* cvol = (float2*)d_out;
        float2* cks  = cvol + NVOX;
        int n4 = (2 * NVOX) / 4;
        zero_kernel<<<(n4 + 255) / 256, 256, 0, stream>>>((float4*)cvol, n4);
        long long total = (long long)M * 343;
        int vb = (int)((total + 255) / 256);
        voxelize_kernel<<<vb, 256, 0, stream>>>(centers, log_scales, rho_r,
                                                rho_i, (float*)cvol, M);
        fft_y_kernel<<<NZd * NXd, 128, 0, stream>>>(cvol, cks);
        fft_x_kernel<<<NZd * NYd, 128, 0, stream>>>(cks);
        fft_z_kernel<<<NXd * NYd, 64, 0, stream>>>(cks, mask, nullptr);
    }
}